// Round 20
// baseline (400.140 us; speedup 1.0000x reference)
//
#include <hip/hip_runtime.h>

#define B_TOT 262144
#define HID   256
#define NHEAD 8
#define BR    64       // rows per block
#define NTHR  256      // 4 waves; wave owns 16 batch rows end-to-end

typedef __bf16 bf16_t;
typedef __attribute__((ext_vector_type(8))) __bf16 bf16x8;
typedef __attribute__((ext_vector_type(4))) float  f32x4;

// d_ws layout (bf16): 32 sequential PHASES of 16 KB. byte = ph*16384 + c*1024 + lane*16
//   ph = 3h+0 (Q) / 3h+1 (K) / 3h+2 (V), h in 0..7 : c = ks*2 + half
//        element = W[h*32 + PI(lane&15,half)][ks*32 + (lane>>4)*8 .. +8]
//        PI(m,half) = (m>>2)*8 + half*4 + (m&3)
//        (PI => attention-mix C-frag holds CONTIGUOUS true features -> out-proj B-frag)
//   ph = 24+ks (Wo) : c = jt; element = Wo[jt*16+(lane&15)][ks*32+(lane>>4)*8 ..+8]
// QKV phases (0..23) staged to LDS (16 KB = 4 gload_lds16/thread, counted vmcnt(4)).
// Wo phases (24..31) are read DIRECTLY from L2 into registers per wave (no LDS,
// no barriers in the tail) — X registers are dead there, freeing the VGPRs.

#define PHASE_SYNC(N)                                                  \
  do {                                                                 \
    asm volatile("s_waitcnt vmcnt(" #N ") lgkmcnt(0)" ::: "memory");   \
    __builtin_amdgcn_s_barrier();                                      \
  } while (0)

static __device__ __forceinline__ f32x4 mfma16(bf16x8 a, bf16x8 b, f32x4 c) {
  return __builtin_amdgcn_mfma_f32_16x16x32_bf16(a, b, c, 0, 0, 0);
}

static __device__ __forceinline__ bf16x8 cvt8(float4 a, float4 b) {
  bf16x8 r;
  r[0] = (bf16_t)a.x; r[1] = (bf16_t)a.y; r[2] = (bf16_t)a.z; r[3] = (bf16_t)a.w;
  r[4] = (bf16_t)b.x; r[5] = (bf16_t)b.y; r[6] = (bf16_t)b.z; r[7] = (bf16_t)b.w;
  return r;
}

// opaque register pin: forbids rematerialization of the producing loads
static __device__ __forceinline__ bf16x8 pin8(bf16x8 v) {
  f32x4 t = __builtin_bit_cast(f32x4, v);
  asm volatile("" : "+v"(t));
  return __builtin_bit_cast(bf16x8, t);
}

typedef __attribute__((address_space(3))) void lds_void;
typedef __attribute__((address_space(1))) void gbl_void;
static __device__ __forceinline__ void gload_lds16(const void* g, void* l) {
  __builtin_amdgcn_global_load_lds((gbl_void*)g, (lds_void*)l, 16, 0, 0);
}

// ---- one-shot weight pack (flat 32-phase layout, unchanged) ----
__global__ __launch_bounds__(256) void pack_weights(
    const float* __restrict__ Wq, const float* __restrict__ Wk,
    const float* __restrict__ Wv, const float* __restrict__ Wo,
    bf16_t* __restrict__ ws) {
  const int t     = blockIdx.x * 256 + threadIdx.x;
  const int lane  = t & 63;
  const int chunk = t >> 6;
  const int l15 = lane & 15, lg = lane >> 4;
  const float* src;
  int row, col;
  if (chunk < 384) {
    const int ph = chunk >> 4;
    const int c  = chunk & 15;
    const int h = ph / 3, w = ph % 3;
    const int ks = c >> 1, half = c & 1;
    src = (w == 0) ? Wq : (w == 1) ? Wk : Wv;
    row = h * 32 + (l15 >> 2) * 8 + half * 4 + (l15 & 3);   // PI permutation
    col = ks * 32 + lg * 8;
  } else {
    const int c  = chunk - 384;
    const int ks = c >> 4, jt = c & 15;
    src = Wo;
    row = jt * 16 + l15;
    col = ks * 32 + lg * 8;
  }
  const float* p = src + (size_t)row * HID + col;
  *(bf16x8*)(ws + (size_t)t * 8) = cvt8(*(const float4*)p, *(const float4*)(p + 4));
}

__global__ __launch_bounds__(NTHR, 2) void fused_local_aug(
    const float* __restrict__ fine, const float* __restrict__ coarse,
    const float* __restrict__ motif, const bf16_t* __restrict__ wpk,
    const float* __restrict__ bo, float* __restrict__ out) {
  __shared__ char wbuf[49152];   // 3 x 16 KB (QKV staging only)

  const int tid  = threadIdx.x;
  const int lane = tid & 63;
  const int wave = tid >> 6;
  const int l15  = lane & 15;
  const int lg   = lane >> 4;
  const size_t mrow = (size_t)blockIdx.x * BR + wave * 16 + l15;

  auto stage = [&](int ph) {     // ph in [0,23] only
    char* dst = wbuf + (ph % 3) * 16384 + tid * 16;
    const char* src = (const char*)wpk + (size_t)ph * 16384 + tid * 16;
#pragma unroll
    for (int i = 0; i < 4; ++i)
      gload_lds16(src + i * 4096, dst + i * 4096);
  };

  stage(0);
  stage(1);

  bf16x8 xm[8], xf[8], xc[8];
  {
    const float* pm = motif  + mrow * HID + lg * 8;
    const float* pf = fine   + mrow * HID + lg * 8;
    const float* pc = coarse + mrow * HID + lg * 8;
#pragma unroll
    for (int s = 0; s < 8; ++s) {
      xm[s] = pin8(cvt8(*(const float4*)(pm + s * 32), *(const float4*)(pm + s * 32 + 4)));
      xf[s] = pin8(cvt8(*(const float4*)(pf + s * 32), *(const float4*)(pf + s * 32 + 4)));
      xc[s] = pin8(cvt8(*(const float4*)(pc + s * 32), *(const float4*)(pc + s * 32 + 4)));
    }
  }
  __syncthreads();   // full drain once: phases 0,1 staged for all waves

  bf16x8 mfrag[NHEAD];
  const f32x4 z4 = {0.f, 0.f, 0.f, 0.f};

  // double accumulator sets: softmax of head h-1 runs inside head h's Q phase
  f32x4 aQ0[2], aQ1[2], aK10[2], aK11[2], aK20[2], aK21[2],
        aV10[2], aV11[2], aV20[2], aV21[2];

#pragma unroll
  for (int h = 0; h < NHEAD; ++h) {
    const int cur = h & 1, prv = cur ^ 1;   // compile-time after unroll
    {  // -- phase Q (p = 3h): MFMA cluster, then DEFERRED softmax of head h-1 --
      const int p = 3 * h;
      if (p > 0) PHASE_SYNC(4);
      stage(p + 2);                         // p+2 = 3h+2 <= 23 always
      aQ0[cur] = z4; aQ1[cur] = z4;
      const char* pb = wbuf + (p % 3) * 16384 + lane * 16;
      __builtin_amdgcn_s_setprio(1);
#pragma unroll
      for (int ks = 0; ks < 8; ++ks) {
        bf16x8 q0 = *(const bf16x8*)(pb + ks * 2048);
        bf16x8 q1 = *(const bf16x8*)(pb + ks * 2048 + 1024);
        aQ0[cur] = mfma16(q0, xm[ks], aQ0[cur]);
        aQ1[cur] = mfma16(q1, xm[ks], aQ1[cur]);
      }
      __builtin_amdgcn_s_setprio(0);
      if (h > 0) {   // softmax + mix for head h-1 (overlaps this phase's MFMAs)
        float s1 = 0.f, s2 = 0.f;
#pragma unroll
        for (int r = 0; r < 4; ++r) {
          s1 += aQ0[prv][r] * aK10[prv][r] + aQ1[prv][r] * aK11[prv][r];
          s2 += aQ0[prv][r] * aK20[prv][r] + aQ1[prv][r] * aK21[prv][r];
        }
        s1 += __shfl_xor(s1, 16); s1 += __shfl_xor(s1, 32);
        s2 += __shfl_xor(s2, 16); s2 += __shfl_xor(s2, 32);
        s1 *= (1.0f / 32.0f);  s2 *= (1.0f / 32.0f);   // reference divides by d_k
        const float mx = fmaxf(s1, s2);
        const float e1 = __expf(s1 - mx), e2 = __expf(s2 - mx);
        const float a1 = e1 / (e1 + e2);
        const float a2 = 1.0f - a1;
        bf16x8 t;
#pragma unroll
        for (int r = 0; r < 4; ++r) {
          t[r]     = (bf16_t)(a1 * aV10[prv][r] + a2 * aV20[prv][r]);
          t[r + 4] = (bf16_t)(a1 * aV11[prv][r] + a2 * aV21[prv][r]);
        }
        mfrag[h - 1] = t;
      }
    }
    {  // -- phase K (p = 3h+1) --
      const int p = 3 * h + 1;
      PHASE_SYNC(4);
      if (p + 2 <= 23) stage(p + 2);        // skip at h=7 (no Wo staging)
      aK10[cur] = z4; aK11[cur] = z4; aK20[cur] = z4; aK21[cur] = z4;
      const char* pb = wbuf + (p % 3) * 16384 + lane * 16;
      __builtin_amdgcn_s_setprio(1);
#pragma unroll
      for (int ks = 0; ks < 8; ++ks) {
        bf16x8 k0 = *(const bf16x8*)(pb + ks * 2048);
        bf16x8 k1 = *(const bf16x8*)(pb + ks * 2048 + 1024);
        aK10[cur] = mfma16(k0, xf[ks], aK10[cur]);
        aK11[cur] = mfma16(k1, xf[ks], aK11[cur]);
        aK20[cur] = mfma16(k0, xc[ks], aK20[cur]);
        aK21[cur] = mfma16(k1, xc[ks], aK21[cur]);
      }
      __builtin_amdgcn_s_setprio(0);
    }
    {  // -- phase V (p = 3h+2) --
      const int p = 3 * h + 2;
      if (p == 23) { PHASE_SYNC(0); }       // last stage (23) issued at p=21
      else         { PHASE_SYNC(4); }
      if (p + 2 <= 23) stage(p + 2);        // skip at h>=7
      aV10[cur] = z4; aV11[cur] = z4; aV20[cur] = z4; aV21[cur] = z4;
      const char* pb = wbuf + (p % 3) * 16384 + lane * 16;
      __builtin_amdgcn_s_setprio(1);
#pragma unroll
      for (int ks = 0; ks < 8; ++ks) {
        bf16x8 v0 = *(const bf16x8*)(pb + ks * 2048);
        bf16x8 v1 = *(const bf16x8*)(pb + ks * 2048 + 1024);
        aV10[cur] = mfma16(v0, xf[ks], aV10[cur]);
        aV11[cur] = mfma16(v1, xf[ks], aV11[cur]);
        aV20[cur] = mfma16(v0, xc[ks], aV20[cur]);
        aV21[cur] = mfma16(v1, xc[ks], aV21[cur]);
      }
      __builtin_amdgcn_s_setprio(0);
    }
  }
  {  // softmax + mix for the last head (h = 7, set index 1)
    const int prv = 1;
    float s1 = 0.f, s2 = 0.f;
#pragma unroll
    for (int r = 0; r < 4; ++r) {
      s1 += aQ0[prv][r] * aK10[prv][r] + aQ1[prv][r] * aK11[prv][r];
      s2 += aQ0[prv][r] * aK20[prv][r] + aQ1[prv][r] * aK21[prv][r];
    }
    s1 += __shfl_xor(s1, 16); s1 += __shfl_xor(s1, 32);
    s2 += __shfl_xor(s2, 16); s2 += __shfl_xor(s2, 32);
    s1 *= (1.0f / 32.0f);  s2 *= (1.0f / 32.0f);
    const float mx = fmaxf(s1, s2);
    const float e1 = __expf(s1 - mx), e2 = __expf(s2 - mx);
    const float a1 = e1 / (e1 + e2);
    const float a2 = 1.0f - a1;
    bf16x8 t;
#pragma unroll
    for (int r = 0; r < 4; ++r) {
      t[r]     = (bf16_t)(a1 * aV10[prv][r] + a2 * aV20[prv][r]);
      t[r + 4] = (bf16_t)(a1 * aV11[prv][r] + a2 * aV21[prv][r]);
    }
    mfrag[NHEAD - 1] = t;
  }

  // ---- output projection: Wo streamed L2 -> registers, wave-private,
  //      NO barriers / NO LDS in the tail (X registers are dead => headroom).
  //      Full unroll lets the scheduler hoist phase wp+1 loads over wp MFMAs.
  f32x4 acc[16];
#pragma unroll
  for (int jt = 0; jt < 16; ++jt) acc[jt] = z4;

  const char* wob = (const char*)wpk + (size_t)24 * 16384 + lane * 16;
#pragma unroll
  for (int wp = 0; wp < 8; ++wp) {
    bf16x8 w[16];
#pragma unroll
    for (int c = 0; c < 16; ++c)
      w[c] = *(const bf16x8*)(wob + (size_t)wp * 16384 + c * 1024);
    bf16x8 m = mfrag[wp];
    __builtin_amdgcn_s_setprio(1);
#pragma unroll
    for (int jt = 0; jt < 16; ++jt)
      acc[jt] = mfma16(w[jt], m, acc[jt]);
    __builtin_amdgcn_s_setprio(0);
  }

  // epilogue: bias + NT stores; lane writes 16B chunks of its own full row
#pragma unroll
  for (int jt = 0; jt < 16; ++jt) {
    const int jj = jt * 16 + lg * 4;
    const float4 b4 = *(const float4*)(bo + jj);
    f32x4 o;
    o[0] = acc[jt][0] + b4.x;
    o[1] = acc[jt][1] + b4.y;
    o[2] = acc[jt][2] + b4.z;
    o[3] = acc[jt][3] + b4.w;
    __builtin_nontemporal_store(o, (f32x4*)(out + mrow * HID + jj));
  }
}

extern "C" void kernel_launch(void* const* d_in, const int* in_sizes, int n_in,
                              void* d_out, int out_size, void* d_ws, size_t ws_size,
                              hipStream_t stream) {
  (void)in_sizes; (void)n_in; (void)ws_size; (void)out_size;
  const float* fine   = (const float*)d_in[0];
  const float* coarse = (const float*)d_in[1];
  const float* motif  = (const float*)d_in[2];
  const float* Wq     = (const float*)d_in[3];
  const float* Wk     = (const float*)d_in[4];
  const float* Wv     = (const float*)d_in[5];
  const float* Wo     = (const float*)d_in[6];
  const float* bo     = (const float*)d_in[7];
  float* out          = (float*)d_out;
  bf16_t* wpk         = (bf16_t*)d_ws;

  pack_weights<<<128, 256, 0, stream>>>(Wq, Wk, Wv, Wo, wpk);
  fused_local_aug<<<B_TOT / BR, NTHR, 0, stream>>>(fine, coarse, motif, wpk, bo, out);
}

// Round 21
// 344.323 us; speedup vs baseline: 1.1621x; 1.1621x over previous
//
#include <hip/hip_runtime.h>

#define B_TOT 262144
#define HID   256
#define NHEAD 8
#define BR    64       // rows per block
#define NTHR  256      // 4 waves; wave owns 16 batch rows end-to-end

typedef __bf16 bf16_t;
typedef __attribute__((ext_vector_type(8))) __bf16 bf16x8;
typedef __attribute__((ext_vector_type(4))) float  f32x4;

// d_ws layout (bf16): 32 sequential PHASES of 16 KB. byte = ph*16384 + c*1024 + lane*16
//   ph = 3h+0 (Q) / 3h+1 (K) / 3h+2 (V), h in 0..7 : c = ks*2 + half
//        element = W[h*32 + PI(lane&15,half)][ks*32 + (lane>>4)*8 .. +8]
//        PI(m,half) = (m>>2)*8 + half*4 + (m&3)
//        (PI => attention-mix C-frag holds CONTIGUOUS true features -> out-proj B-frag)
//   ph = 24+ks (Wo) : c = jt; element = Wo[jt*16+(lane&15)][ks*32+(lane>>4)*8 ..+8]
// Every phase = 16 KB = 4 gload_lds16/thread -> uniform counted vmcnt(4).

// Counted wait + barrier. lgkmcnt(0): all ds_reads of the retiring buffer are
// complete before anyone passes the barrier (stage(p+2) then can't clobber them).
// NO sched_barrier: "memory" clobber already orders memory ops; register-only
// MFMAs may sink across the barrier, which is harmless and lets the scheduler
// overlap softmax / stage issue with MFMA clusters.
#define PHASE_SYNC(N)                                                  \
  do {                                                                 \
    asm volatile("s_waitcnt vmcnt(" #N ") lgkmcnt(0)" ::: "memory");   \
    __builtin_amdgcn_s_barrier();                                      \
  } while (0)

static __device__ __forceinline__ f32x4 mfma16(bf16x8 a, bf16x8 b, f32x4 c) {
  return __builtin_amdgcn_mfma_f32_16x16x32_bf16(a, b, c, 0, 0, 0);
}

static __device__ __forceinline__ bf16x8 cvt8(float4 a, float4 b) {
  bf16x8 r;
  r[0] = (bf16_t)a.x; r[1] = (bf16_t)a.y; r[2] = (bf16_t)a.z; r[3] = (bf16_t)a.w;
  r[4] = (bf16_t)b.x; r[5] = (bf16_t)b.y; r[6] = (bf16_t)b.z; r[7] = (bf16_t)b.w;
  return r;
}

// opaque register pin: forbids rematerialization of the producing loads
static __device__ __forceinline__ bf16x8 pin8(bf16x8 v) {
  f32x4 t = __builtin_bit_cast(f32x4, v);
  asm volatile("" : "+v"(t));
  return __builtin_bit_cast(bf16x8, t);
}

typedef __attribute__((address_space(3))) void lds_void;
typedef __attribute__((address_space(1))) void gbl_void;
static __device__ __forceinline__ void gload_lds16(const void* g, void* l) {
  __builtin_amdgcn_global_load_lds((gbl_void*)g, (lds_void*)l, 16, 0, 0);
}

// ---- one-shot weight pack (flat 32-phase layout) ----
__global__ __launch_bounds__(256) void pack_weights(
    const float* __restrict__ Wq, const float* __restrict__ Wk,
    const float* __restrict__ Wv, const float* __restrict__ Wo,
    bf16_t* __restrict__ ws) {
  const int t     = blockIdx.x * 256 + threadIdx.x;
  const int lane  = t & 63;
  const int chunk = t >> 6;
  const int l15 = lane & 15, lg = lane >> 4;
  const float* src;
  int row, col;
  if (chunk < 384) {
    const int ph = chunk >> 4;
    const int c  = chunk & 15;
    const int h = ph / 3, w = ph % 3;
    const int ks = c >> 1, half = c & 1;
    src = (w == 0) ? Wq : (w == 1) ? Wk : Wv;
    row = h * 32 + (l15 >> 2) * 8 + half * 4 + (l15 & 3);   // PI permutation
    col = ks * 32 + lg * 8;
  } else {
    const int c  = chunk - 384;
    const int ks = c >> 4, jt = c & 15;
    src = Wo;
    row = jt * 16 + l15;
    col = ks * 32 + lg * 8;
  }
  const float* p = src + (size_t)row * HID + col;
  *(bf16x8*)(ws + (size_t)t * 8) = cvt8(*(const float4*)p, *(const float4*)(p + 4));
}

__global__ __launch_bounds__(NTHR, 2) void fused_local_aug(
    const float* __restrict__ fine, const float* __restrict__ coarse,
    const float* __restrict__ motif, const bf16_t* __restrict__ wpk,
    const float* __restrict__ bo, float* __restrict__ out) {
  __shared__ char wbuf[49152];   // 3 x 16 KB

  const int tid  = threadIdx.x;
  const int lane = tid & 63;
  const int wave = tid >> 6;
  const int l15  = lane & 15;
  const int lg   = lane >> 4;
  const size_t mrow = (size_t)blockIdx.x * BR + wave * 16 + l15;

  auto stage = [&](int ph) {
    char* dst = wbuf + (ph % 3) * 16384 + tid * 16;
    const char* src = (const char*)wpk + (size_t)ph * 16384 + tid * 16;
#pragma unroll
    for (int i = 0; i < 4; ++i)
      gload_lds16(src + i * 4096, dst + i * 4096);
  };

  stage(0);
  stage(1);

  bf16x8 xm[8], xf[8], xc[8];
  {
    const float* pm = motif  + mrow * HID + lg * 8;
    const float* pf = fine   + mrow * HID + lg * 8;
    const float* pc = coarse + mrow * HID + lg * 8;
#pragma unroll
    for (int s = 0; s < 8; ++s) {
      xm[s] = pin8(cvt8(*(const float4*)(pm + s * 32), *(const float4*)(pm + s * 32 + 4)));
      xf[s] = pin8(cvt8(*(const float4*)(pf + s * 32), *(const float4*)(pf + s * 32 + 4)));
      xc[s] = pin8(cvt8(*(const float4*)(pc + s * 32), *(const float4*)(pc + s * 32 + 4)));
    }
  }
  __syncthreads();   // full drain once: phases 0,1 staged for all waves

  bf16x8 mfrag[NHEAD];
  const f32x4 z4 = {0.f, 0.f, 0.f, 0.f};

  // double accumulator sets: softmax of head h-1 runs inside head h's Q phase
  f32x4 aQ0[2], aQ1[2], aK10[2], aK11[2], aK20[2], aK21[2],
        aV10[2], aV11[2], aV20[2], aV21[2];

#pragma unroll
  for (int h = 0; h < NHEAD; ++h) {
    const int cur = h & 1, prv = cur ^ 1;   // compile-time after unroll
    {  // -- phase Q (p = 3h): MFMA cluster, then DEFERRED softmax of head h-1 --
      const int p = 3 * h;
      if (p > 0) PHASE_SYNC(4);
      stage(p + 2);
      aQ0[cur] = z4; aQ1[cur] = z4;
      const char* pb = wbuf + (p % 3) * 16384 + lane * 16;
      __builtin_amdgcn_s_setprio(1);
#pragma unroll
      for (int ks = 0; ks < 8; ++ks) {
        bf16x8 q0 = *(const bf16x8*)(pb + ks * 2048);
        bf16x8 q1 = *(const bf16x8*)(pb + ks * 2048 + 1024);
        aQ0[cur] = mfma16(q0, xm[ks], aQ0[cur]);
        aQ1[cur] = mfma16(q1, xm[ks], aQ1[cur]);
      }
      __builtin_amdgcn_s_setprio(0);
      if (h > 0) {   // softmax + mix for head h-1 (overlaps this phase's MFMAs)
        float s1 = 0.f, s2 = 0.f;
#pragma unroll
        for (int r = 0; r < 4; ++r) {
          s1 += aQ0[prv][r] * aK10[prv][r] + aQ1[prv][r] * aK11[prv][r];
          s2 += aQ0[prv][r] * aK20[prv][r] + aQ1[prv][r] * aK21[prv][r];
        }
        s1 += __shfl_xor(s1, 16); s1 += __shfl_xor(s1, 32);
        s2 += __shfl_xor(s2, 16); s2 += __shfl_xor(s2, 32);
        s1 *= (1.0f / 32.0f);  s2 *= (1.0f / 32.0f);   // reference divides by d_k
        const float mx = fmaxf(s1, s2);
        const float e1 = __expf(s1 - mx), e2 = __expf(s2 - mx);
        const float a1 = e1 / (e1 + e2);
        const float a2 = 1.0f - a1;
        bf16x8 t;
#pragma unroll
        for (int r = 0; r < 4; ++r) {
          t[r]     = (bf16_t)(a1 * aV10[prv][r] + a2 * aV20[prv][r]);
          t[r + 4] = (bf16_t)(a1 * aV11[prv][r] + a2 * aV21[prv][r]);
        }
        mfrag[h - 1] = t;
      }
    }
    {  // -- phase K (p = 3h+1) --
      const int p = 3 * h + 1;
      PHASE_SYNC(4);
      stage(p + 2);
      aK10[cur] = z4; aK11[cur] = z4; aK20[cur] = z4; aK21[cur] = z4;
      const char* pb = wbuf + (p % 3) * 16384 + lane * 16;
      __builtin_amdgcn_s_setprio(1);
#pragma unroll
      for (int ks = 0; ks < 8; ++ks) {
        bf16x8 k0 = *(const bf16x8*)(pb + ks * 2048);
        bf16x8 k1 = *(const bf16x8*)(pb + ks * 2048 + 1024);
        aK10[cur] = mfma16(k0, xf[ks], aK10[cur]);
        aK11[cur] = mfma16(k1, xf[ks], aK11[cur]);
        aK20[cur] = mfma16(k0, xc[ks], aK20[cur]);
        aK21[cur] = mfma16(k1, xc[ks], aK21[cur]);
      }
      __builtin_amdgcn_s_setprio(0);
    }
    {  // -- phase V (p = 3h+2) --
      const int p = 3 * h + 2;
      PHASE_SYNC(4);
      stage(p + 2);
      aV10[cur] = z4; aV11[cur] = z4; aV20[cur] = z4; aV21[cur] = z4;
      const char* pb = wbuf + (p % 3) * 16384 + lane * 16;
      __builtin_amdgcn_s_setprio(1);
#pragma unroll
      for (int ks = 0; ks < 8; ++ks) {
        bf16x8 v0 = *(const bf16x8*)(pb + ks * 2048);
        bf16x8 v1 = *(const bf16x8*)(pb + ks * 2048 + 1024);
        aV10[cur] = mfma16(v0, xf[ks], aV10[cur]);
        aV11[cur] = mfma16(v1, xf[ks], aV11[cur]);
        aV20[cur] = mfma16(v0, xc[ks], aV20[cur]);
        aV21[cur] = mfma16(v1, xc[ks], aV21[cur]);
      }
      __builtin_amdgcn_s_setprio(0);
    }
  }
  {  // softmax + mix for the last head (h = 7, set index 1)
    const int prv = 1;
    float s1 = 0.f, s2 = 0.f;
#pragma unroll
    for (int r = 0; r < 4; ++r) {
      s1 += aQ0[prv][r] * aK10[prv][r] + aQ1[prv][r] * aK11[prv][r];
      s2 += aQ0[prv][r] * aK20[prv][r] + aQ1[prv][r] * aK21[prv][r];
    }
    s1 += __shfl_xor(s1, 16); s1 += __shfl_xor(s1, 32);
    s2 += __shfl_xor(s2, 16); s2 += __shfl_xor(s2, 32);
    s1 *= (1.0f / 32.0f);  s2 *= (1.0f / 32.0f);
    const float mx = fmaxf(s1, s2);
    const float e1 = __expf(s1 - mx), e2 = __expf(s2 - mx);
    const float a1 = e1 / (e1 + e2);
    const float a2 = 1.0f - a1;
    bf16x8 t;
#pragma unroll
    for (int r = 0; r < 4; ++r) {
      t[r]     = (bf16_t)(a1 * aV10[prv][r] + a2 * aV20[prv][r]);
      t[r + 4] = (bf16_t)(a1 * aV11[prv][r] + a2 * aV21[prv][r]);
    }
    mfrag[NHEAD - 1] = t;
  }

  // ---- output projection: 8 pipelined Wo phases (p = 24+wp) ----
  f32x4 acc[16];
#pragma unroll
  for (int jt = 0; jt < 16; ++jt) acc[jt] = z4;

#pragma unroll
  for (int wp = 0; wp < 8; ++wp) {
    const int p = 24 + wp;
    if (wp == 7) { PHASE_SYNC(0); } else { PHASE_SYNC(4); }
    if (wp < 6) stage(p + 2);
    bf16x8 m = mfrag[wp];
    const char* pb = wbuf + (p % 3) * 16384 + lane * 16;
    __builtin_amdgcn_s_setprio(1);
#pragma unroll
    for (int jt = 0; jt < 16; ++jt) {
      bf16x8 wf = *(const bf16x8*)(pb + jt * 1024);
      acc[jt] = mfma16(wf, m, acc[jt]);
    }
    __builtin_amdgcn_s_setprio(0);
  }

  // epilogue: bias + NT stores; lane writes 16B chunks of its own full row
#pragma unroll
  for (int jt = 0; jt < 16; ++jt) {
    const int jj = jt * 16 + lg * 4;
    const float4 b4 = *(const float4*)(bo + jj);
    f32x4 o;
    o[0] = acc[jt][0] + b4.x;
    o[1] = acc[jt][1] + b4.y;
    o[2] = acc[jt][2] + b4.z;
    o[3] = acc[jt][3] + b4.w;
    __builtin_nontemporal_store(o, (f32x4*)(out + mrow * HID + jj));
  }
}

extern "C" void kernel_launch(void* const* d_in, const int* in_sizes, int n_in,
                              void* d_out, int out_size, void* d_ws, size_t ws_size,
                              hipStream_t stream) {
  (void)in_sizes; (void)n_in; (void)ws_size; (void)out_size;
  const float* fine   = (const float*)d_in[0];
  const float* coarse = (const float*)d_in[1];
  const float* motif  = (const float*)d_in[2];
  const float* Wq     = (const float*)d_in[3];
  const float* Wk     = (const float*)d_in[4];
  const float* Wv     = (const float*)d_in[5];
  const float* Wo     = (const float*)d_in[6];
  const float* bo     = (const float*)d_in[7];
  float* out          = (float*)d_out;
  bf16_t* wpk         = (bf16_t*)d_ws;

  pack_weights<<<128, 256, 0, stream>>>(Wq, Wk, Wv, Wo, wpk);
  fused_local_aug<<<B_TOT / BR, NTHR, 0, stream>>>(fine, coarse, motif, wpk, bo, out);
}

// Round 22
// 341.650 us; speedup vs baseline: 1.1712x; 1.0078x over previous
//
#include <hip/hip_runtime.h>

#define B_TOT 262144
#define HID   256
#define NHEAD 8
#define BR    64       // rows per block
#define NTHR  256      // 4 waves; wave owns 16 batch rows end-to-end

typedef __bf16 bf16_t;
typedef __attribute__((ext_vector_type(8))) __bf16 bf16x8;
typedef __attribute__((ext_vector_type(4))) float  f32x4;

// d_ws layout (bf16): 32 sequential PHASES of 16 KB. byte = ph*16384 + c*1024 + lane*16
//   ph = 3h+0 (Q) / 3h+1 (K) / 3h+2 (V), h in 0..7 : c = ks*2 + half
//        element = W[h*32 + PI(lane&15,half)][ks*32 + (lane>>4)*8 .. +8]
//        PI(m,half) = (m>>2)*8 + half*4 + (m&3)
//        (PI => attention-mix C-frag holds CONTIGUOUS true features -> out-proj B-frag)
//   ph = 24+ks (Wo) : c = jt; element = Wo[jt*16+(lane&15)][ks*32+(lane>>4)*8 ..+8]
// 4 LDS buffers x 16 KB; phase p reads buffer p&3; stage issued 3 AHEAD
// (stage(p+3) inside phase p). At entry of p, vmcnt(4) leaves only stage(p+2)
// outstanding => stage(p) AND stage(p+1) complete: phase p's in-phase reads are
// safe, and the FIRST HALF of p+1's fragments is prefetched into registers
// during p (kills the post-barrier ds_read->MFMA head-of-phase bubble).
// WAR: stage(p+3) writes buffer (p-1)&3, whose reads (in-phase during p-1,
// prefetch during p-2) are drained by lgkmcnt(0)+barrier at entry of p.

#define PHASE_SYNC(N)                                                  \
  do {                                                                 \
    asm volatile("s_waitcnt vmcnt(" #N ") lgkmcnt(0)" ::: "memory");   \
    __builtin_amdgcn_s_barrier();                                      \
  } while (0)

static __device__ __forceinline__ f32x4 mfma16(bf16x8 a, bf16x8 b, f32x4 c) {
  return __builtin_amdgcn_mfma_f32_16x16x32_bf16(a, b, c, 0, 0, 0);
}

static __device__ __forceinline__ bf16x8 cvt8(float4 a, float4 b) {
  bf16x8 r;
  r[0] = (bf16_t)a.x; r[1] = (bf16_t)a.y; r[2] = (bf16_t)a.z; r[3] = (bf16_t)a.w;
  r[4] = (bf16_t)b.x; r[5] = (bf16_t)b.y; r[6] = (bf16_t)b.z; r[7] = (bf16_t)b.w;
  return r;
}

// opaque register pin: forbids rematerialization of the producing loads
static __device__ __forceinline__ bf16x8 pin8(bf16x8 v) {
  f32x4 t = __builtin_bit_cast(f32x4, v);
  asm volatile("" : "+v"(t));
  return __builtin_bit_cast(bf16x8, t);
}

typedef __attribute__((address_space(3))) void lds_void;
typedef __attribute__((address_space(1))) void gbl_void;
static __device__ __forceinline__ void gload_lds16(const void* g, void* l) {
  __builtin_amdgcn_global_load_lds((gbl_void*)g, (lds_void*)l, 16, 0, 0);
}

// ---- one-shot weight pack (flat 32-phase layout, unchanged from R13) ----
__global__ __launch_bounds__(256) void pack_weights(
    const float* __restrict__ Wq, const float* __restrict__ Wk,
    const float* __restrict__ Wv, const float* __restrict__ Wo,
    bf16_t* __restrict__ ws) {
  const int t     = blockIdx.x * 256 + threadIdx.x;
  const int lane  = t & 63;
  const int chunk = t >> 6;
  const int l15 = lane & 15, lg = lane >> 4;
  const float* src;
  int row, col;
  if (chunk < 384) {
    const int ph = chunk >> 4;
    const int c  = chunk & 15;
    const int h = ph / 3, w = ph % 3;
    const int ks = c >> 1, half = c & 1;
    src = (w == 0) ? Wq : (w == 1) ? Wk : Wv;
    row = h * 32 + (l15 >> 2) * 8 + half * 4 + (l15 & 3);   // PI permutation
    col = ks * 32 + lg * 8;
  } else {
    const int c  = chunk - 384;
    const int ks = c >> 4, jt = c & 15;
    src = Wo;
    row = jt * 16 + l15;
    col = ks * 32 + lg * 8;
  }
  const float* p = src + (size_t)row * HID + col;
  *(bf16x8*)(ws + (size_t)t * 8) = cvt8(*(const float4*)p, *(const float4*)(p + 4));
}

__global__ __launch_bounds__(NTHR, 2) void fused_local_aug(
    const float* __restrict__ fine, const float* __restrict__ coarse,
    const float* __restrict__ motif, const bf16_t* __restrict__ wpk,
    const float* __restrict__ bo, float* __restrict__ out) {
  __shared__ char wbuf[65536];   // 4 x 16 KB -> 2 blocks/CU

  const int tid  = threadIdx.x;
  const int lane = tid & 63;
  const int wave = tid >> 6;
  const int l15  = lane & 15;
  const int lg   = lane >> 4;
  const size_t mrow = (size_t)blockIdx.x * BR + wave * 16 + l15;

  auto stage = [&](int ph) {
    char* dst = wbuf + (ph & 3) * 16384 + tid * 16;
    const char* src = (const char*)wpk + (size_t)ph * 16384 + tid * 16;
#pragma unroll
    for (int i = 0; i < 4; ++i)
      gload_lds16(src + i * 4096, dst + i * 4096);
  };

  stage(0);
  stage(1);
  stage(2);

  bf16x8 xm[8], xf[8], xc[8];
  {
    const float* pm = motif  + mrow * HID + lg * 8;
    const float* pf = fine   + mrow * HID + lg * 8;
    const float* pc = coarse + mrow * HID + lg * 8;
#pragma unroll
    for (int s = 0; s < 8; ++s) {
      xm[s] = pin8(cvt8(*(const float4*)(pm + s * 32), *(const float4*)(pm + s * 32 + 4)));
      xf[s] = pin8(cvt8(*(const float4*)(pf + s * 32), *(const float4*)(pf + s * 32 + 4)));
      xc[s] = pin8(cvt8(*(const float4*)(pc + s * 32), *(const float4*)(pc + s * 32 + 4)));
    }
  }
  __syncthreads();   // full drain once: phases 0,1,2 staged for all waves

  // cross-phase W prefetch registers: first half (frags c=0..7) of each phase,
  // double-buffered by phase parity (all indices unroll-constant)
  bf16x8 wpre[2][8];
  {
    const char* pb = wbuf + lane * 16;   // phase 0, buffer 0
#pragma unroll
    for (int c = 0; c < 8; ++c) wpre[0][c] = *(const bf16x8*)(pb + c * 1024);
  }

  bf16x8 mfrag[NHEAD];
  const f32x4 z4 = {0.f, 0.f, 0.f, 0.f};

  // SINGLE accumulator set; scores partial-summed in-lane at K-phase end (ps),
  // softmax finish deferred into next head's Q phase (uses ps + surviving aV).
  f32x4 aQ0, aQ1, aK10, aK11, aK20, aK21, aV10, aV11, aV20, aV21;
  float ps1 = 0.f, ps2 = 0.f;

  auto finish = [&](int hh) {
    float s1 = ps1, s2 = ps2;
    s1 += __shfl_xor(s1, 16); s1 += __shfl_xor(s1, 32);
    s2 += __shfl_xor(s2, 16); s2 += __shfl_xor(s2, 32);
    s1 *= (1.0f / 32.0f);  s2 *= (1.0f / 32.0f);   // reference divides by d_k
    const float mx = fmaxf(s1, s2);
    const float e1 = __expf(s1 - mx), e2 = __expf(s2 - mx);
    const float a1 = e1 / (e1 + e2);
    const float a2 = 1.0f - a1;
    bf16x8 t;
#pragma unroll
    for (int r = 0; r < 4; ++r) {
      t[r]     = (bf16_t)(a1 * aV10[r] + a2 * aV20[r]);
      t[r + 4] = (bf16_t)(a1 * aV11[r] + a2 * aV21[r]);
    }
    mfrag[hh] = t;
  };

  auto prefetch_next = [&](int p) {   // first half of phase p+1 -> wpre[(p+1)&1]
    const char* pn = wbuf + ((p + 1) & 3) * 16384 + lane * 16;
#pragma unroll
    for (int c = 0; c < 8; ++c)
      wpre[(p + 1) & 1][c] = *(const bf16x8*)(pn + c * 1024);
  };

#pragma unroll
  for (int h = 0; h < NHEAD; ++h) {
    {  // -- phase Q (p = 3h) --
      const int p = 3 * h;
      if (p > 0) PHASE_SYNC(4);
      stage(p + 3);
      aQ0 = z4; aQ1 = z4;
      const char* pb = wbuf + (p & 3) * 16384 + lane * 16;
      __builtin_amdgcn_s_setprio(1);
#pragma unroll
      for (int ks = 0; ks < 4; ++ks) {          // first half: prefetched regs
        aQ0 = mfma16(wpre[p & 1][ks * 2],     xm[ks], aQ0);
        aQ1 = mfma16(wpre[p & 1][ks * 2 + 1], xm[ks], aQ1);
      }
#pragma unroll
      for (int ks = 4; ks < 8; ++ks) {          // second half: in-phase reads
        bf16x8 q0 = *(const bf16x8*)(pb + ks * 2048);
        bf16x8 q1 = *(const bf16x8*)(pb + ks * 2048 + 1024);
        aQ0 = mfma16(q0, xm[ks], aQ0);
        aQ1 = mfma16(q1, xm[ks], aQ1);
      }
      __builtin_amdgcn_s_setprio(0);
      prefetch_next(p);
      if (h > 0) finish(h - 1);                 // overlaps with this phase
    }
    {  // -- phase K (p = 3h+1): scores partial at end --
      const int p = 3 * h + 1;
      PHASE_SYNC(4);
      stage(p + 3);
      aK10 = z4; aK11 = z4; aK20 = z4; aK21 = z4;
      const char* pb = wbuf + (p & 3) * 16384 + lane * 16;
      __builtin_amdgcn_s_setprio(1);
#pragma unroll
      for (int ks = 0; ks < 4; ++ks) {
        bf16x8 k0 = wpre[p & 1][ks * 2];
        bf16x8 k1 = wpre[p & 1][ks * 2 + 1];
        aK10 = mfma16(k0, xf[ks], aK10);
        aK11 = mfma16(k1, xf[ks], aK11);
        aK20 = mfma16(k0, xc[ks], aK20);
        aK21 = mfma16(k1, xc[ks], aK21);
      }
#pragma unroll
      for (int ks = 4; ks < 8; ++ks) {
        bf16x8 k0 = *(const bf16x8*)(pb + ks * 2048);
        bf16x8 k1 = *(const bf16x8*)(pb + ks * 2048 + 1024);
        aK10 = mfma16(k0, xf[ks], aK10);
        aK11 = mfma16(k1, xf[ks], aK11);
        aK20 = mfma16(k0, xc[ks], aK20);
        aK21 = mfma16(k1, xc[ks], aK21);
      }
      __builtin_amdgcn_s_setprio(0);
      prefetch_next(p);
      {  // in-lane score partials (aQ, aK dead after this)
        float s1 = 0.f, s2 = 0.f;
#pragma unroll
        for (int r = 0; r < 4; ++r) {
          s1 += aQ0[r] * aK10[r] + aQ1[r] * aK11[r];
          s2 += aQ0[r] * aK20[r] + aQ1[r] * aK21[r];
        }
        ps1 = s1; ps2 = s2;
      }
    }
    {  // -- phase V (p = 3h+2) --
      const int p = 3 * h + 2;
      PHASE_SYNC(4);
      stage(p + 3);
      aV10 = z4; aV11 = z4; aV20 = z4; aV21 = z4;
      const char* pb = wbuf + (p & 3) * 16384 + lane * 16;
      __builtin_amdgcn_s_setprio(1);
#pragma unroll
      for (int ks = 0; ks < 4; ++ks) {
        bf16x8 v0 = wpre[p & 1][ks * 2];
        bf16x8 v1 = wpre[p & 1][ks * 2 + 1];
        aV10 = mfma16(v0, xf[ks], aV10);
        aV11 = mfma16(v1, xf[ks], aV11);
        aV20 = mfma16(v0, xc[ks], aV20);
        aV21 = mfma16(v1, xc[ks], aV21);
      }
#pragma unroll
      for (int ks = 4; ks < 8; ++ks) {
        bf16x8 v0 = *(const bf16x8*)(pb + ks * 2048);
        bf16x8 v1 = *(const bf16x8*)(pb + ks * 2048 + 1024);
        aV10 = mfma16(v0, xf[ks], aV10);
        aV11 = mfma16(v1, xf[ks], aV11);
        aV20 = mfma16(v0, xc[ks], aV20);
        aV21 = mfma16(v1, xc[ks], aV21);
      }
      __builtin_amdgcn_s_setprio(0);
      prefetch_next(p);   // h<7: Q(h+1); h=7: Wo phase 24 (same frag pattern)
    }
  }
  finish(NHEAD - 1);

  // ---- output projection: 8 Wo phases (p = 24+wp) ----
  f32x4 acc[16];
#pragma unroll
  for (int jt = 0; jt < 16; ++jt) acc[jt] = z4;

#pragma unroll
  for (int wp = 0; wp < 8; ++wp) {
    const int p = 24 + wp;
    if (wp <= 5) { PHASE_SYNC(4); } else { PHASE_SYNC(0); }
    if (wp <= 4) stage(p + 3);           // stages 27..31
    bf16x8 m = mfrag[wp];
    const char* pb = wbuf + (p & 3) * 16384 + lane * 16;
    __builtin_amdgcn_s_setprio(1);
#pragma unroll
    for (int jt = 0; jt < 8; ++jt)       // first half: prefetched regs
      acc[jt] = mfma16(wpre[p & 1][jt], m, acc[jt]);
#pragma unroll
    for (int jt = 8; jt < 16; ++jt) {    // second half: in-phase reads
      bf16x8 wf = *(const bf16x8*)(pb + jt * 1024);
      acc[jt] = mfma16(wf, m, acc[jt]);
    }
    __builtin_amdgcn_s_setprio(0);
    if (wp < 7) prefetch_next(p);
  }

  // epilogue: bias + NT stores; lane writes 16B chunks of its own full row
#pragma unroll
  for (int jt = 0; jt < 16; ++jt) {
    const int jj = jt * 16 + lg * 4;
    const float4 b4 = *(const float4*)(bo + jj);
    f32x4 o;
    o[0] = acc[jt][0] + b4.x;
    o[1] = acc[jt][1] + b4.y;
    o[2] = acc[jt][2] + b4.z;
    o[3] = acc[jt][3] + b4.w;
    __builtin_nontemporal_store(o, (f32x4*)(out + mrow * HID + jj));
  }
}

extern "C" void kernel_launch(void* const* d_in, const int* in_sizes, int n_in,
                              void* d_out, int out_size, void* d_ws, size_t ws_size,
                              hipStream_t stream) {
  (void)in_sizes; (void)n_in; (void)ws_size; (void)out_size;
  const float* fine   = (const float*)d_in[0];
  const float* coarse = (const float*)d_in[1];
  const float* motif  = (const float*)d_in[2];
  const float* Wq     = (const float*)d_in[3];
  const float* Wk     = (const float*)d_in[4];
  const float* Wv     = (const float*)d_in[5];
  const float* Wo     = (const float*)d_in[6];
  const float* bo     = (const float*)d_in[7];
  float* out          = (float*)d_out;
  bf16_t* wpk         = (bf16_t*)d_ws;

  pack_weights<<<128, 256, 0, stream>>>(Wq, Wk, Wv, Wo, wpk);
  fused_local_aug<<<B_TOT / BR, NTHR, 0, stream>>>(fine, coarse, motif, wpk, bo, out);
}